// Round 1
// baseline (3483.278 us; speedup 1.0000x reference)
//
#include <hip/hip_runtime.h>
#include <hip/hip_bf16.h>

#define NN 100000
#define NE 1200000
#define DIN 128
#define HDIM 64

// ---------------- degree / norm ----------------
__global__ __launch_bounds__(256) void k_init_deg(float* deg) {
    int i = blockIdx.x * 256 + threadIdx.x;
    if (i < NN) deg[i] = 1.0f;  // self loop
}

__global__ __launch_bounds__(256) void k_edge_deg(const int* __restrict__ col, float* deg) {
    int e = blockIdx.x * 256 + threadIdx.x;
    if (e < NE) atomicAdd(&deg[col[e]], 1.0f);
}

__global__ __launch_bounds__(256) void k_rsqrt(float* deg) {
    int i = blockIdx.x * 256 + threadIdx.x;
    if (i < NN) deg[i] = rsqrtf(deg[i]);  // deg >= 1 always
}

// ---------------- GEMM: Y[n][j] = sum_d X[n][d]*W[j][d] + b[j], j<64 ----------------
template<int D, int BN>
__global__ __launch_bounds__(256) void k_gemm(const float* __restrict__ X,
                                              const float* __restrict__ W,
                                              const float* __restrict__ bias,
                                              float* __restrict__ Y, int n_nodes) {
    __shared__ float Wt[D * 64];         // Wt[d*64+j]
    __shared__ float Xl[BN * (D + 1)];   // padded rows -> bank spread
    const int tid = threadIdx.x;
    const int n0 = blockIdx.x * BN;

    for (int idx = tid; idx < 64 * D; idx += 256) {
        int j = idx / D, d = idx - j * D;
        Wt[d * 64 + j] = W[idx];
    }
    for (int idx = tid; idx < BN * D; idx += 256) {
        int nl = idx / D, d = idx - nl * D;
        int n = n0 + nl; if (n >= n_nodes) n = n_nodes - 1;
        Xl[nl * (D + 1) + d] = X[(size_t)n * D + d];
    }
    __syncthreads();

    const int j0 = (tid & 15) * 4;
    const int nl = tid >> 4;             // 0..15
    constexpr int K = BN / 16;
    float acc[K][4];
    float b0 = 0.f, b1 = 0.f, b2 = 0.f, b3 = 0.f;
    if (bias) { b0 = bias[j0]; b1 = bias[j0 + 1]; b2 = bias[j0 + 2]; b3 = bias[j0 + 3]; }
    #pragma unroll
    for (int k = 0; k < K; k++) { acc[k][0] = b0; acc[k][1] = b1; acc[k][2] = b2; acc[k][3] = b3; }

    #pragma unroll 4
    for (int d = 0; d < D; d++) {
        const float4 w4 = *(const float4*)&Wt[d * 64 + j0];
        #pragma unroll
        for (int k = 0; k < K; k++) {
            float xv = Xl[(nl + 16 * k) * (D + 1) + d];
            acc[k][0] += xv * w4.x; acc[k][1] += xv * w4.y;
            acc[k][2] += xv * w4.z; acc[k][3] += xv * w4.w;
        }
    }
    #pragma unroll
    for (int k = 0; k < K; k++) {
        int n = n0 + nl + 16 * k;
        if (n < n_nodes)
            *(float4*)&Y[(size_t)n * 64 + j0] = make_float4(acc[k][0], acc[k][1], acc[k][2], acc[k][3]);
    }
}

// ---------------- aggregation ----------------
// hC[n][f] = hB[n][f]*dinv[n]^2 + b[f]   (self loop + bias)
__global__ __launch_bounds__(256) void k_agg_init(const float* __restrict__ hB,
                                                  const float* __restrict__ dinv,
                                                  const float* __restrict__ cb,
                                                  float* __restrict__ hC) {
    int i = blockIdx.x * 256 + threadIdx.x;  // over NN*64 exactly
    int n = i >> 6, f = i & 63;
    float dv = dinv[n];
    hC[i] = hB[i] * dv * dv + cb[f];
}

// hC[col[e]][f] += hB[row[e]][f] * dinv[row]*dinv[col]; 16 threads/edge, 4 feats each
__global__ __launch_bounds__(256) void k_agg_edges(const float* __restrict__ hB,
                                                   const float* __restrict__ dinv,
                                                   const int* __restrict__ row,
                                                   const int* __restrict__ col,
                                                   float* __restrict__ hC) {
    int e = blockIdx.x * 16 + (threadIdx.x >> 4);
    if (e >= NE) return;
    int f4 = (threadIdx.x & 15) * 4;
    int r = row[e], c = col[e];
    float nrm = dinv[r] * dinv[c];
    const float4 hv = *(const float4*)(hB + (size_t)r * 64 + f4);
    float* dst = hC + (size_t)c * 64 + f4;
    atomicAdd(dst + 0, hv.x * nrm);
    atomicAdd(dst + 1, hv.y * nrm);
    atomicAdd(dst + 2, hv.z * nrm);
    atomicAdd(dst + 3, hv.w * nrm);
}

// hA[i] = relu(hC[i]*s[f] + b[f]) (+ hA[i] if residual)
__global__ __launch_bounds__(256) void k_post(const float* __restrict__ hC,
                                              const float* __restrict__ g,
                                              const float* __restrict__ bb,
                                              float* __restrict__ hA, int residual) {
    int i = blockIdx.x * 256 + threadIdx.x;  // over NN*64 exactly
    int f = i & 63;
    float s = g[f] * rsqrtf(1.0f + 1e-5f);
    float v = hC[i] * s + bb[f];
    v = fmaxf(v, 0.0f);
    hA[i] = residual ? (v + hA[i]) : v;
}

// ---------------- head: byp + concat-head + clips ----------------
__global__ __launch_bounds__(256) void k_head(const float* __restrict__ x,
                                              const float* __restrict__ hA,
                                              const float* __restrict__ bypW,
                                              const float* __restrict__ bypb,
                                              const float* __restrict__ headW,
                                              const float* __restrict__ headb,
                                              float* __restrict__ out) {
    __shared__ float BW[3 * 128];
    __shared__ float HW[3 * 67];
    __shared__ float BB[3], HB[3];
    int tid = threadIdx.x;
    for (int i = tid; i < 384; i += 256) BW[i] = bypW[i];
    for (int i = tid; i < 201; i += 256) HW[i] = headW[i];
    if (tid < 3) { BB[tid] = bypb[tid]; HB[tid] = headb[tid]; }
    __syncthreads();
    int n = blockIdx.x * 256 + tid;
    if (n >= NN) return;

    float b0 = BB[0], b1 = BB[1], b2 = BB[2];
    const float4* xr = (const float4*)(x + (size_t)n * 128);
    #pragma unroll
    for (int i = 0; i < 32; i++) {
        float4 v = xr[i];
        int d = i * 4;
        b0 += v.x * BW[d] + v.y * BW[d + 1] + v.z * BW[d + 2] + v.w * BW[d + 3];
        b1 += v.x * BW[128 + d] + v.y * BW[128 + d + 1] + v.z * BW[128 + d + 2] + v.w * BW[128 + d + 3];
        b2 += v.x * BW[256 + d] + v.y * BW[256 + d + 1] + v.z * BW[256 + d + 2] + v.w * BW[256 + d + 3];
    }
    float p0 = HB[0], p1 = HB[1], p2 = HB[2];
    const float4* hr = (const float4*)(hA + (size_t)n * 64);
    #pragma unroll
    for (int i = 0; i < 16; i++) {
        float4 v = hr[i];
        int f = i * 4;
        p0 += v.x * HW[f] + v.y * HW[f + 1] + v.z * HW[f + 2] + v.w * HW[f + 3];
        p1 += v.x * HW[67 + f] + v.y * HW[67 + f + 1] + v.z * HW[67 + f + 2] + v.w * HW[67 + f + 3];
        p2 += v.x * HW[134 + f] + v.y * HW[134 + f + 1] + v.z * HW[134 + f + 2] + v.w * HW[134 + f + 3];
    }
    p0 += b0 * HW[64] + b1 * HW[65] + b2 * HW[66];
    p1 += b0 * HW[67 + 64] + b1 * HW[67 + 65] + b2 * HW[67 + 66];
    p2 += b0 * HW[134 + 64] + b1 * HW[134 + 65] + b2 * HW[134 + 66];

    float kappa = fminf(fmaxf(p0 * 5.0f + 2.5f, 0.2f), 10.0f);
    float alpha = p1;
    float tau = fminf(fmaxf(p2 + 0.5f, 0.05f), 2.0f);
    float* o = out + (size_t)n * 3;
    o[0] = kappa; o[1] = alpha; o[2] = tau;
}

extern "C" void kernel_launch(void* const* d_in, const int* in_sizes, int n_in,
                              void* d_out, int out_size, void* d_ws, size_t ws_size,
                              hipStream_t stream) {
    const float* x     = (const float*)d_in[0];
    const int*   ei    = (const int*)d_in[1];
    const int*   row   = ei;
    const int*   col   = ei + NE;
    const float* projW = (const float*)d_in[2];
    const float* projb = (const float*)d_in[3];
    const float* convW[3] = { (const float*)d_in[4], (const float*)d_in[8],  (const float*)d_in[12] };
    const float* convb[3] = { (const float*)d_in[5], (const float*)d_in[9],  (const float*)d_in[13] };
    const float* bng[3]   = { (const float*)d_in[6], (const float*)d_in[10], (const float*)d_in[14] };
    const float* bnb[3]   = { (const float*)d_in[7], (const float*)d_in[11], (const float*)d_in[15] };
    const float* bypW  = (const float*)d_in[16];
    const float* bypb  = (const float*)d_in[17];
    const float* headW = (const float*)d_in[18];
    const float* headb = (const float*)d_in[19];
    float* out = (float*)d_out;

    float* ws   = (float*)d_ws;
    float* dinv = ws;                       // NN floats (deg then dinv in place)
    float* hA   = ws + 102400;              // NN*64
    float* hB   = hA + (size_t)NN * 64;     // NN*64
    float* hC   = hB + (size_t)NN * 64;     // NN*64

    k_init_deg<<<(NN + 255) / 256, 256, 0, stream>>>(dinv);
    k_edge_deg<<<(NE + 255) / 256, 256, 0, stream>>>(col, dinv);
    k_rsqrt<<<(NN + 255) / 256, 256, 0, stream>>>(dinv);

    // proj: hA = x @ projW.T + projb
    k_gemm<128, 32><<<NN / 32, 256, 0, stream>>>(x, projW, projb, hA, NN);

    for (int l = 0; l < 3; l++) {
        k_gemm<64, 64><<<(NN + 63) / 64, 256, 0, stream>>>(hA, convW[l], nullptr, hB, NN);
        k_agg_init<<<(NN * 64) / 256, 256, 0, stream>>>(hB, dinv, convb[l], hC);
        k_agg_edges<<<NE / 16, 256, 0, stream>>>(hB, dinv, row, col, hC);
        k_post<<<(NN * 64) / 256, 256, 0, stream>>>(hC, bng[l], bnb[l], hA, l < 2 ? 1 : 0);
    }

    k_head<<<(NN + 255) / 256, 256, 0, stream>>>(x, hA, bypW, bypb, headW, headb, out);
}

// Round 2
// 678.578 us; speedup vs baseline: 5.1332x; 5.1332x over previous
//
#include <hip/hip_runtime.h>
#include <hip/hip_bf16.h>

#define NN 100000
#define NE 1200000
#define DIN 128
#define HDIM 64
#define NB_SCAN ((NN + 255) / 256)   // 391

// ---------------- CSR build ----------------
__global__ __launch_bounds__(256) void k_zero(int* counts) {
    int i = blockIdx.x * 256 + threadIdx.x;
    if (i < NN) counts[i] = 0;
}

__global__ __launch_bounds__(256) void k_hist(const int* __restrict__ col, int* counts) {
    int e = blockIdx.x * 256 + threadIdx.x;
    if (e < NE) atomicAdd(&counts[col[e]], 1);
}

// dinv[n] = rsqrt(counts[n] + 1)   (self loop)
__global__ __launch_bounds__(256) void k_dinv(const int* __restrict__ counts, float* dinv) {
    int i = blockIdx.x * 256 + threadIdx.x;
    if (i < NN) dinv[i] = rsqrtf((float)counts[i] + 1.0f);
}

// per-block exclusive scan of counts -> off, block totals -> bsum
__global__ __launch_bounds__(256) void k_scan1(const int* __restrict__ counts,
                                               int* __restrict__ off, int* __restrict__ bsum) {
    __shared__ int s[256];
    int tid = threadIdx.x;
    int i = blockIdx.x * 256 + tid;
    int v = (i < NN) ? counts[i] : 0;
    s[tid] = v;
    __syncthreads();
    #pragma unroll
    for (int d = 1; d < 256; d <<= 1) {
        int t = (tid >= d) ? s[tid - d] : 0;
        __syncthreads();
        s[tid] += t;
        __syncthreads();
    }
    if (i < NN) off[i] = s[tid] - v;   // exclusive
    if (tid == 255) bsum[blockIdx.x] = s[255];
}

// single-block exclusive scan of bsum[NB_SCAN]
__global__ __launch_bounds__(512) void k_scan2(int* bsum) {
    __shared__ int s[512];
    int tid = threadIdx.x;
    int v = (tid < NB_SCAN) ? bsum[tid] : 0;
    s[tid] = v;
    __syncthreads();
    #pragma unroll
    for (int d = 1; d < 512; d <<= 1) {
        int t = (tid >= d) ? s[tid - d] : 0;
        __syncthreads();
        s[tid] += t;
        __syncthreads();
    }
    if (tid < NB_SCAN) bsum[tid] = s[tid] - v;  // exclusive
}

__global__ __launch_bounds__(256) void k_scan3(int* __restrict__ off, const int* __restrict__ bsum,
                                               int* __restrict__ cursor) {
    int i = blockIdx.x * 256 + threadIdx.x;
    if (i < NN) {
        int o = off[i] + bsum[blockIdx.x];
        off[i] = o;
        cursor[i] = o;
    }
    if (i == 0) off[NN] = NE;
}

__global__ __launch_bounds__(256) void k_scatter(const int* __restrict__ row,
                                                 const int* __restrict__ col,
                                                 int* __restrict__ cursor,
                                                 int* __restrict__ csr_row) {
    int e = blockIdx.x * 256 + threadIdx.x;
    if (e >= NE) return;
    int pos = atomicAdd(&cursor[col[e]], 1);
    csr_row[pos] = row[e];
}

// ---------------- GEMM: Y[n][j] = (sum_d X[n][d]*W[j][d] + b[j]) * (dinv?dinv[n]:1) ----------------
template<int D, int BN>
__global__ __launch_bounds__(256) void k_gemm(const float* __restrict__ X,
                                              const float* __restrict__ W,
                                              const float* __restrict__ bias,
                                              const float* __restrict__ dinv,
                                              float* __restrict__ Y, int n_nodes) {
    __shared__ float Wt[D * 64];         // Wt[d*64+j]
    __shared__ float Xl[BN * (D + 1)];   // padded rows -> bank spread
    const int tid = threadIdx.x;
    const int n0 = blockIdx.x * BN;

    for (int idx = tid; idx < 64 * D; idx += 256) {
        int j = idx / D, d = idx - j * D;
        Wt[d * 64 + j] = W[idx];
    }
    for (int idx = tid; idx < BN * D; idx += 256) {
        int nl = idx / D, d = idx - nl * D;
        int n = n0 + nl; if (n >= n_nodes) n = n_nodes - 1;
        Xl[nl * (D + 1) + d] = X[(size_t)n * D + d];
    }
    __syncthreads();

    const int j0 = (tid & 15) * 4;
    const int nl = tid >> 4;             // 0..15
    constexpr int K = BN / 16;
    float acc[K][4];
    float b0 = 0.f, b1 = 0.f, b2 = 0.f, b3 = 0.f;
    if (bias) { b0 = bias[j0]; b1 = bias[j0 + 1]; b2 = bias[j0 + 2]; b3 = bias[j0 + 3]; }
    #pragma unroll
    for (int k = 0; k < K; k++) { acc[k][0] = b0; acc[k][1] = b1; acc[k][2] = b2; acc[k][3] = b3; }

    #pragma unroll 4
    for (int d = 0; d < D; d++) {
        const float4 w4 = *(const float4*)&Wt[d * 64 + j0];
        #pragma unroll
        for (int k = 0; k < K; k++) {
            float xv = Xl[(nl + 16 * k) * (D + 1) + d];
            acc[k][0] += xv * w4.x; acc[k][1] += xv * w4.y;
            acc[k][2] += xv * w4.z; acc[k][3] += xv * w4.w;
        }
    }
    #pragma unroll
    for (int k = 0; k < K; k++) {
        int n = n0 + nl + 16 * k;
        if (n < n_nodes) {
            float s = dinv ? dinv[n] : 1.0f;
            *(float4*)&Y[(size_t)n * 64 + j0] =
                make_float4(acc[k][0] * s, acc[k][1] * s, acc[k][2] * s, acc[k][3] * s);
        }
    }
}

// ---------------- fused pull-aggregation + bias + bn + relu + residual ----------------
// hBs[r][f] = (hA @ W.T)[r][f] * dinv[r]  (pre-scaled by gemm epilogue)
// hA[n][f]  = relu( (  (hBs[n][f] + sum_e hBs[csr_row[e]][f]) * dinv[n] + convb[f] ) * bns[f] + bnb[f] )
//             (+ hA_old[n][f] if residual)
__global__ __launch_bounds__(256) void k_gather(const float* __restrict__ hBs,
                                                const float* __restrict__ dinv,
                                                const int* __restrict__ off,
                                                const int* __restrict__ csr_row,
                                                const float* __restrict__ convb,
                                                const float* __restrict__ g,
                                                const float* __restrict__ bb,
                                                float* __restrict__ hA, int residual) {
    int n = blockIdx.x * 4 + (threadIdx.x >> 6);
    if (n >= NN) return;
    int f = threadIdx.x & 63;

    float acc = hBs[(size_t)n * 64 + f];   // self loop term (already *dinv[n] once)
    int e = off[n], eEnd = off[n + 1];
    if (e < eEnd) {
        int r = csr_row[e];
        while (++e < eEnd) {
            int rn = csr_row[e];           // prefetch next index
            acc += hBs[(size_t)r * 64 + f];
            r = rn;
        }
        acc += hBs[(size_t)r * 64 + f];
    }
    float s = g[f] * rsqrtf(1.0f + 1e-5f);
    float v = (acc * dinv[n] + convb[f]) * s + bb[f];
    v = fmaxf(v, 0.0f);
    size_t o = (size_t)n * 64 + f;
    hA[o] = residual ? (v + hA[o]) : v;
}

// ---------------- head: byp + concat-head + clips ----------------
__global__ __launch_bounds__(256) void k_head(const float* __restrict__ x,
                                              const float* __restrict__ hA,
                                              const float* __restrict__ bypW,
                                              const float* __restrict__ bypb,
                                              const float* __restrict__ headW,
                                              const float* __restrict__ headb,
                                              float* __restrict__ out) {
    __shared__ float BW[3 * 128];
    __shared__ float HW[3 * 67];
    __shared__ float BB[3], HB[3];
    int tid = threadIdx.x;
    for (int i = tid; i < 384; i += 256) BW[i] = bypW[i];
    for (int i = tid; i < 201; i += 256) HW[i] = headW[i];
    if (tid < 3) { BB[tid] = bypb[tid]; HB[tid] = headb[tid]; }
    __syncthreads();
    int n = blockIdx.x * 256 + tid;
    if (n >= NN) return;

    float b0 = BB[0], b1 = BB[1], b2 = BB[2];
    const float4* xr = (const float4*)(x + (size_t)n * 128);
    #pragma unroll
    for (int i = 0; i < 32; i++) {
        float4 v = xr[i];
        int d = i * 4;
        b0 += v.x * BW[d] + v.y * BW[d + 1] + v.z * BW[d + 2] + v.w * BW[d + 3];
        b1 += v.x * BW[128 + d] + v.y * BW[128 + d + 1] + v.z * BW[128 + d + 2] + v.w * BW[128 + d + 3];
        b2 += v.x * BW[256 + d] + v.y * BW[256 + d + 1] + v.z * BW[256 + d + 2] + v.w * BW[256 + d + 3];
    }
    float p0 = HB[0], p1 = HB[1], p2 = HB[2];
    const float4* hr = (const float4*)(hA + (size_t)n * 64);
    #pragma unroll
    for (int i = 0; i < 16; i++) {
        float4 v = hr[i];
        int f = i * 4;
        p0 += v.x * HW[f] + v.y * HW[f + 1] + v.z * HW[f + 2] + v.w * HW[f + 3];
        p1 += v.x * HW[67 + f] + v.y * HW[67 + f + 1] + v.z * HW[67 + f + 2] + v.w * HW[67 + f + 3];
        p2 += v.x * HW[134 + f] + v.y * HW[134 + f + 1] + v.z * HW[134 + f + 2] + v.w * HW[134 + f + 3];
    }
    p0 += b0 * HW[64] + b1 * HW[65] + b2 * HW[66];
    p1 += b0 * HW[67 + 64] + b1 * HW[67 + 65] + b2 * HW[67 + 66];
    p2 += b0 * HW[134 + 64] + b1 * HW[134 + 65] + b2 * HW[134 + 66];

    float kappa = fminf(fmaxf(p0 * 5.0f + 2.5f, 0.2f), 10.0f);
    float alpha = p1;
    float tau = fminf(fmaxf(p2 + 0.5f, 0.05f), 2.0f);
    float* o = out + (size_t)n * 3;
    o[0] = kappa; o[1] = alpha; o[2] = tau;
}

extern "C" void kernel_launch(void* const* d_in, const int* in_sizes, int n_in,
                              void* d_out, int out_size, void* d_ws, size_t ws_size,
                              hipStream_t stream) {
    const float* x     = (const float*)d_in[0];
    const int*   ei    = (const int*)d_in[1];
    const int*   row   = ei;
    const int*   col   = ei + NE;
    const float* projW = (const float*)d_in[2];
    const float* projb = (const float*)d_in[3];
    const float* convW[3] = { (const float*)d_in[4], (const float*)d_in[8],  (const float*)d_in[12] };
    const float* convb[3] = { (const float*)d_in[5], (const float*)d_in[9],  (const float*)d_in[13] };
    const float* bng[3]   = { (const float*)d_in[6], (const float*)d_in[10], (const float*)d_in[14] };
    const float* bnb[3]   = { (const float*)d_in[7], (const float*)d_in[11], (const float*)d_in[15] };
    const float* bypW  = (const float*)d_in[16];
    const float* bypb  = (const float*)d_in[17];
    const float* headW = (const float*)d_in[18];
    const float* headb = (const float*)d_in[19];
    float* out = (float*)d_out;

    float* ws   = (float*)d_ws;
    float* dinv = ws;                                  // NN floats (pad to 102400)
    float* hA   = ws + 102400;                         // NN*64
    float* hB   = hA + (size_t)NN * 64;                // NN*64 (dinv-scaled gemm out)
    int*   off     = (int*)(hB + (size_t)NN * 64);     // NN+1
    int*   cursor  = off + NN + 1;                     // NN (also counts)
    int*   csr_row = cursor + NN;                      // NE
    int*   bsum    = csr_row + NE;                     // NB_SCAN (<=512)

    int* counts = cursor;  // reuse: counts first, then overwritten with cursor in scan3

    // CSR build + dinv
    k_zero<<<(NN + 255) / 256, 256, 0, stream>>>(counts);
    k_hist<<<(NE + 255) / 256, 256, 0, stream>>>(col, counts);
    k_dinv<<<(NN + 255) / 256, 256, 0, stream>>>(counts, dinv);
    k_scan1<<<NB_SCAN, 256, 0, stream>>>(counts, off, bsum);
    k_scan2<<<1, 512, 0, stream>>>(bsum);
    k_scan3<<<NB_SCAN, 256, 0, stream>>>(off, bsum, cursor);
    k_scatter<<<(NE + 255) / 256, 256, 0, stream>>>(row, col, cursor, csr_row);

    // proj: hA = x @ projW.T + projb   (no dinv scale)
    k_gemm<128, 32><<<NN / 32, 256, 0, stream>>>(x, projW, projb, nullptr, hA, NN);

    for (int l = 0; l < 3; l++) {
        // hB = (hA @ convW.T) * dinv  (bias deferred to gather)
        k_gemm<64, 64><<<(NN + 63) / 64, 256, 0, stream>>>(hA, convW[l], nullptr, dinv, hB, NN);
        k_gather<<<(NN + 3) / 4, 256, 0, stream>>>(hB, dinv, off, csr_row, convb[l],
                                                   bng[l], bnb[l], hA, l < 2 ? 1 : 0);
    }

    k_head<<<(NN + 255) / 256, 256, 0, stream>>>(x, hA, bypW, bypb, headW, headb, out);
}

// Round 3
// 594.152 us; speedup vs baseline: 5.8626x; 1.1421x over previous
//
#include <hip/hip_runtime.h>
#include <hip/hip_fp16.h>

#define NN 100000
#define NE 1200000
#define NB_SCAN ((NN + 255) / 256)   // 391

struct alignas(8) Half4 { __half2 lo, hi; };

// ---------------- CSR build ----------------
__global__ __launch_bounds__(256) void k_zero(int* counts) {
    int i = blockIdx.x * 256 + threadIdx.x;
    if (i < NN) counts[i] = 0;
}

__global__ __launch_bounds__(256) void k_hist(const int* __restrict__ col, int* counts) {
    int e = blockIdx.x * 256 + threadIdx.x;
    if (e < NE) atomicAdd(&counts[col[e]], 1);
}

// per-block exclusive scan of counts -> off, block totals -> bsum; also dinv = rsqrt(counts+1)
__global__ __launch_bounds__(256) void k_scan1(const int* __restrict__ counts,
                                               int* __restrict__ off, int* __restrict__ bsum,
                                               float* __restrict__ dinv) {
    __shared__ int s[256];
    int tid = threadIdx.x;
    int i = blockIdx.x * 256 + tid;
    int v = (i < NN) ? counts[i] : 0;
    if (i < NN) dinv[i] = rsqrtf((float)v + 1.0f);
    s[tid] = v;
    __syncthreads();
    #pragma unroll
    for (int d = 1; d < 256; d <<= 1) {
        int t = (tid >= d) ? s[tid - d] : 0;
        __syncthreads();
        s[tid] += t;
        __syncthreads();
    }
    if (i < NN) off[i] = s[tid] - v;   // exclusive
    if (tid == 255) bsum[blockIdx.x] = s[255];
}

__global__ __launch_bounds__(512) void k_scan2(int* bsum) {
    __shared__ int s[512];
    int tid = threadIdx.x;
    int v = (tid < NB_SCAN) ? bsum[tid] : 0;
    s[tid] = v;
    __syncthreads();
    #pragma unroll
    for (int d = 1; d < 512; d <<= 1) {
        int t = (tid >= d) ? s[tid - d] : 0;
        __syncthreads();
        s[tid] += t;
        __syncthreads();
    }
    if (tid < NB_SCAN) bsum[tid] = s[tid] - v;  // exclusive
}

__global__ __launch_bounds__(256) void k_scan3(int* __restrict__ off, const int* __restrict__ bsum,
                                               int* __restrict__ cursor) {
    int i = blockIdx.x * 256 + threadIdx.x;
    if (i < NN) {
        int o = off[i] + bsum[blockIdx.x];
        off[i] = o;
        cursor[i] = o;
    }
    if (i == 0) off[NN] = NE;
}

__global__ __launch_bounds__(256) void k_scatter(const int* __restrict__ row,
                                                 const int* __restrict__ col,
                                                 int* __restrict__ cursor,
                                                 int* __restrict__ csr_row) {
    int e = blockIdx.x * 256 + threadIdx.x;
    if (e >= NE) return;
    int pos = atomicAdd(&cursor[col[e]], 1);
    csr_row[pos] = row[e];
}

// ---------------- GEMM ----------------
// OUTH: write fp16, scaled by dinv[n].  BYP: also compute byp[n][0..2] = x@bypW.T + bypb.
template<int D, int BN, bool OUTH, bool BYP>
__global__ __launch_bounds__(256) void k_gemm(const float* __restrict__ X,
                                              const float* __restrict__ W,
                                              const float* __restrict__ bias,
                                              const float* __restrict__ dinv,
                                              float* __restrict__ Y,
                                              __half* __restrict__ Yh,
                                              const float* __restrict__ bypW,
                                              const float* __restrict__ bypb,
                                              float* __restrict__ bypOut,
                                              int n_nodes) {
    __shared__ float Wt[D * 64];         // Wt[d*64+j]
    __shared__ float Xl[BN * (D + 1)];   // padded rows
    __shared__ float BWs[BYP ? 387 : 1];
    const int tid = threadIdx.x;
    const int n0 = blockIdx.x * BN;

    for (int idx = tid; idx < 64 * D; idx += 256) {
        int j = idx / D, d = idx - j * D;
        Wt[d * 64 + j] = W[idx];
    }
    for (int idx = tid; idx < BN * D; idx += 256) {
        int nl = idx / D, d = idx - nl * D;
        int n = n0 + nl; if (n >= n_nodes) n = n_nodes - 1;
        Xl[nl * (D + 1) + d] = X[(size_t)n * D + d];
    }
    if constexpr (BYP) {
        for (int idx = tid; idx < 387; idx += 256)
            BWs[idx] = (idx < 384) ? bypW[idx] : bypb[idx - 384];
    }
    __syncthreads();

    const int j0 = (tid & 15) * 4;
    const int nl = tid >> 4;             // 0..15
    constexpr int K = BN / 16;
    float acc[K][4];
    float b0 = 0.f, b1 = 0.f, b2 = 0.f, b3 = 0.f;
    if (bias) { b0 = bias[j0]; b1 = bias[j0 + 1]; b2 = bias[j0 + 2]; b3 = bias[j0 + 3]; }
    #pragma unroll
    for (int k = 0; k < K; k++) { acc[k][0] = b0; acc[k][1] = b1; acc[k][2] = b2; acc[k][3] = b3; }

    #pragma unroll 4
    for (int d = 0; d < D; d++) {
        const float4 w4 = *(const float4*)&Wt[d * 64 + j0];
        #pragma unroll
        for (int k = 0; k < K; k++) {
            float xv = Xl[(nl + 16 * k) * (D + 1) + d];
            acc[k][0] += xv * w4.x; acc[k][1] += xv * w4.y;
            acc[k][2] += xv * w4.z; acc[k][3] += xv * w4.w;
        }
    }
    #pragma unroll
    for (int k = 0; k < K; k++) {
        int n = n0 + nl + 16 * k;
        if (n < n_nodes) {
            if constexpr (OUTH) {
                float s = dinv[n];
                Half4 h;
                h.lo = __floats2half2_rn(acc[k][0] * s, acc[k][1] * s);
                h.hi = __floats2half2_rn(acc[k][2] * s, acc[k][3] * s);
                *(Half4*)&Yh[(size_t)n * 64 + j0] = h;
            } else {
                *(float4*)&Y[(size_t)n * 64 + j0] =
                    make_float4(acc[k][0], acc[k][1], acc[k][2], acc[k][3]);
            }
        }
    }
    if constexpr (BYP) {
        if (tid < 96) {
            int nl2 = tid & 31, o = tid >> 5;
            float b = BWs[384 + o];
            #pragma unroll 8
            for (int d = 0; d < D; d++)
                b += Xl[nl2 * (D + 1) + d] * BWs[o * 128 + d];
            int n = n0 + nl2;
            if (n < n_nodes) bypOut[n * 3 + o] = b;
        }
    }
}

// ---------------- fused pull-aggregation ----------------
// One 64-lane wave per node. lane = (g = lane>>3 edge slot, s = lane&7 feature octet).
// acc = self + sum_edges hBh[row]; epilogue bias+bn+relu (+residual) or fused head.
template<bool RES, bool HEAD>
__global__ __launch_bounds__(256) void k_gather(const __half* __restrict__ hBh,
                                                const float* __restrict__ dinv,
                                                const int* __restrict__ off,
                                                const int* __restrict__ csr_row,
                                                const float* __restrict__ convb,
                                                const float* __restrict__ bng,
                                                const float* __restrict__ bnb,
                                                float* __restrict__ hA,
                                                const float* __restrict__ byp,
                                                const float* __restrict__ headW,
                                                const float* __restrict__ headb,
                                                float* __restrict__ out) {
    __shared__ float HWs[HEAD ? 204 : 1];
    const int tid = threadIdx.x;
    if constexpr (HEAD) {
        for (int i = tid; i < 204; i += 256)
            HWs[i] = (i < 201) ? headW[i] : headb[i - 201];
        __syncthreads();
    }
    const int n = blockIdx.x * 4 + (tid >> 6);   // grid = NN/4 exactly
    const int lane = tid & 63;
    const int g = lane >> 3, s = lane & 7;
    const int f0 = s * 8;

    const int e0 = off[n], eEnd = off[n + 1];
    float acc[8] = {0, 0, 0, 0, 0, 0, 0, 0};
    const int nIter = (eEnd - e0 + 7) >> 3;
    for (int t = 0; t < nIter; ++t) {
        int idx = e0 + t * 8 + g;
        float w = (idx < eEnd) ? 1.0f : 0.0f;
        int idxc = (idx < eEnd) ? idx : (eEnd - 1);
        int r = csr_row[idxc];
        float4 raw = *(const float4*)(hBh + ((size_t)r << 6) + f0);
        const __half2* h2 = (const __half2*)&raw;
        #pragma unroll
        for (int q = 0; q < 4; ++q) {
            float2 f = __half22float2(h2[q]);
            acc[2 * q]     = fmaf(w, f.x, acc[2 * q]);
            acc[2 * q + 1] = fmaf(w, f.y, acc[2 * q + 1]);
        }
    }
    // reduce the 8 edge-groups
    #pragma unroll
    for (int m = 8; m < 64; m <<= 1) {
        #pragma unroll
        for (int j = 0; j < 8; ++j)
            acc[j] += __shfl_xor(acc[j], m, 64);
    }
    // self-loop term
    {
        float4 raw = *(const float4*)(hBh + ((size_t)n << 6) + f0);
        const __half2* h2 = (const __half2*)&raw;
        #pragma unroll
        for (int q = 0; q < 4; ++q) {
            float2 f = __half22float2(h2[q]);
            acc[2 * q]     += f.x;
            acc[2 * q + 1] += f.y;
        }
    }
    const float dv = dinv[n];
    const float bnscale = rsqrtf(1.0f + 1e-5f);
    float v[8];
    #pragma unroll
    for (int j = 0; j < 8; ++j) {
        float sc = bng[f0 + j] * bnscale;
        v[j] = fmaxf((acc[j] * dv + convb[f0 + j]) * sc + bnb[f0 + j], 0.0f);
    }
    if constexpr (!HEAD) {
        if (g == 0) {
            size_t o = ((size_t)n << 6) + f0;
            if constexpr (RES) {
                #pragma unroll
                for (int j = 0; j < 8; ++j) v[j] += hA[o + j];
            }
            *(float4*)&hA[o]     = make_float4(v[0], v[1], v[2], v[3]);
            *(float4*)&hA[o + 4] = make_float4(v[4], v[5], v[6], v[7]);
        }
    } else {
        float p[3];
        #pragma unroll
        for (int o = 0; o < 3; ++o) {
            float t = 0.f;
            #pragma unroll
            for (int j = 0; j < 8; ++j) t += v[j] * HWs[o * 67 + f0 + j];
            p[o] = t;
        }
        #pragma unroll
        for (int m = 1; m < 8; m <<= 1) {
            #pragma unroll
            for (int o = 0; o < 3; ++o) p[o] += __shfl_xor(p[o], m, 64);
        }
        float b0 = byp[n * 3], b1 = byp[n * 3 + 1], b2 = byp[n * 3 + 2];
        #pragma unroll
        for (int o = 0; o < 3; ++o)
            p[o] += b0 * HWs[o * 67 + 64] + b1 * HWs[o * 67 + 65] + b2 * HWs[o * 67 + 66]
                  + HWs[201 + o];
        if (lane == 0) {
            float kappa = fminf(fmaxf(p[0] * 5.0f + 2.5f, 0.2f), 10.0f);
            float tau   = fminf(fmaxf(p[2] + 0.5f, 0.05f), 2.0f);
            out[(size_t)n * 3]     = kappa;
            out[(size_t)n * 3 + 1] = p[1];
            out[(size_t)n * 3 + 2] = tau;
        }
    }
}

extern "C" void kernel_launch(void* const* d_in, const int* in_sizes, int n_in,
                              void* d_out, int out_size, void* d_ws, size_t ws_size,
                              hipStream_t stream) {
    const float* x     = (const float*)d_in[0];
    const int*   ei    = (const int*)d_in[1];
    const int*   row   = ei;
    const int*   col   = ei + NE;
    const float* projW = (const float*)d_in[2];
    const float* projb = (const float*)d_in[3];
    const float* convW[3] = { (const float*)d_in[4], (const float*)d_in[8],  (const float*)d_in[12] };
    const float* convb[3] = { (const float*)d_in[5], (const float*)d_in[9],  (const float*)d_in[13] };
    const float* bng[3]   = { (const float*)d_in[6], (const float*)d_in[10], (const float*)d_in[14] };
    const float* bnb[3]   = { (const float*)d_in[7], (const float*)d_in[11], (const float*)d_in[15] };
    const float* bypW  = (const float*)d_in[16];
    const float* bypb  = (const float*)d_in[17];
    const float* headW = (const float*)d_in[18];
    const float* headb = (const float*)d_in[19];
    float* out = (float*)d_out;

    float*  ws   = (float*)d_ws;
    float*  dinv = ws;                                  // 102400 floats
    float*  hA   = ws + 102400;                         // NN*64 fp32
    __half* hBh  = (__half*)(hA + (size_t)NN * 64);     // NN*64 fp16
    float*  byp  = (float*)(hBh + (size_t)NN * 64);     // NN*3 (+pad)
    int*    off     = (int*)(byp + 300032);             // NN+1
    int*    cursor  = off + NN + 1;                     // NN (counts first)
    int*    csr_row = cursor + NN;                      // NE
    int*    bsum    = csr_row + NE;                     // NB_SCAN

    int* counts = cursor;

    // CSR build + dinv
    k_zero<<<(NN + 255) / 256, 256, 0, stream>>>(counts);
    k_hist<<<(NE + 255) / 256, 256, 0, stream>>>(col, counts);
    k_scan1<<<NB_SCAN, 256, 0, stream>>>(counts, off, bsum, dinv);
    k_scan2<<<1, 512, 0, stream>>>(bsum);
    k_scan3<<<NB_SCAN, 256, 0, stream>>>(off, bsum, cursor);
    k_scatter<<<(NE + 255) / 256, 256, 0, stream>>>(row, col, cursor, csr_row);

    // proj: hA = x @ projW.T + projb  (fp32 out) + byp = x @ bypW.T + bypb
    k_gemm<128, 32, false, true><<<NN / 32, 256, 0, stream>>>(
        x, projW, projb, nullptr, hA, nullptr, bypW, bypb, byp, NN);

    for (int l = 0; l < 3; l++) {
        // hBh = (hA @ convW.T) * dinv   (fp16 out, bias deferred)
        k_gemm<64, 64, true, false><<<(NN + 63) / 64, 256, 0, stream>>>(
            hA, convW[l], nullptr, dinv, nullptr, hBh, nullptr, nullptr, nullptr, NN);
        if (l < 2)
            k_gather<true, false><<<NN / 4, 256, 0, stream>>>(
                hBh, dinv, off, csr_row, convb[l], bng[l], bnb[l], hA,
                nullptr, nullptr, nullptr, nullptr);
        else
            k_gather<false, true><<<NN / 4, 256, 0, stream>>>(
                hBh, dinv, off, csr_row, convb[l], bng[l], bnb[l], nullptr,
                byp, headW, headb, out);
    }
}